// Round 3
// baseline (493.718 us; speedup 1.0000x reference)
//
#include <hip/hip_runtime.h>
#include <math.h>

// SparseMoEALU, MFMA round 3: X state in registers (C-layout), k-dim-permuted
// LDS images so all transposes are b64/b128, block-diag stacked-slot attention.

typedef __bf16 bfrag  __attribute__((ext_vector_type(8)));
typedef __bf16 bf16x4 __attribute__((ext_vector_type(4)));
typedef float  f32x4  __attribute__((ext_vector_type(4)));

#define MFMA16(a,b,c) __builtin_amdgcn_mfma_f32_16x16x32_bf16((a),(b),(c),0,0,0)

constexpr int NB = 16384, NOPS = 37, OP_START = 16;

// ws layout (int32 units for bucketing region)
constexpr int WS_OPARR  = 0;
constexpr int WS_CNT    = 16384;
constexpr int WS_OFF    = 16448;
constexpr int WS_CUR    = 16512;
constexpr int WS_ROWIDX = 16640;
constexpr int WS_INTS   = 33024;   // weight region at byte 132096 (16B aligned)

// bf16 element offsets in weight region (all *2 bytes, 16B aligned)
constexpr int OFF_QKVT = 0;        // [192][64]  rows: 0..63 Q, 64..127 K, 128..191 V
constexpr int OFF_WI1T = 12288;    // 37 x [128][64]
constexpr int OFF_WI2T = 315392;   // 37 x [64][128]
constexpr int OFF_WC1T = 618496;
constexpr int OFF_WC2T = 921600;
constexpr int OFF_WF1T = 1224704;
constexpr int OFF_WF2T = 1527808;
constexpr int OFF_WD1T = 1830912;  // 16 x [128][64]
constexpr int OFF_WD2T = 1961984;  // 16 x [64][128]
constexpr int OFF_WM1T = 2093056;
constexpr int OFF_WM2T = 2224128;

// ---------------- prep kernels ----------------

__global__ void k_zero(int* cnt, int* cur) {
    int t = threadIdx.x;
    if (t < NOPS) { cnt[t] = 0; cur[t] = 0; }
}

// one wave per row: coalesced argmax over the 37 opcode channels
__global__ void k_op(const float* __restrict__ x, int* __restrict__ opArr, int* __restrict__ cnt) {
    int wave = threadIdx.x >> 6, lane = threadIdx.x & 63;
    int row = blockIdx.x * 4 + wave;
    if (row >= NB) return;
    float av = (lane < NOPS) ? x[(size_t)row * 512 + OP_START + lane] : -INFINITY;
    int ai = lane;
    #pragma unroll
    for (int s = 1; s < 64; s <<= 1) {
        float ov = __shfl_xor(av, s);
        int   oi = __shfl_xor(ai, s);
        if (ov > av || (ov == av && oi < ai)) { av = ov; ai = oi; }
    }
    if (lane == 0) { opArr[row] = ai; atomicAdd(&cnt[ai], 1); }
}

__global__ void k_scan(const int* __restrict__ cnt, int* __restrict__ off) {
    if (threadIdx.x == 0) {
        int a = 0;
        for (int o = 0; o < NOPS; ++o) { off[o] = a; a += cnt[o]; }
        off[NOPS] = a;
    }
}

__global__ void k_scatter(const int* __restrict__ opArr, const int* __restrict__ off,
                          int* __restrict__ cur, int* __restrict__ rowIdx) {
    int b = blockIdx.x * 256 + threadIdx.x;
    if (b >= NB) return;
    int op = opArr[b];
    int pos = off[op] + atomicAdd(&cur[op], 1);
    rowIdx[pos] = b;
}

// transpose [R][C] fp32 -> [C][R] bf16 with k-row permutation matching the
// LDS pack order: perm(p) = (p & (R/16-1))*16 + (p >> log2(R/16))
__global__ void k_wt(const float* __restrict__ Wi1, const float* __restrict__ Wi2,
                     const float* __restrict__ Wq,  const float* __restrict__ Wk,
                     const float* __restrict__ Wv,
                     const float* __restrict__ Wc1, const float* __restrict__ Wc2,
                     const float* __restrict__ Wd1, const float* __restrict__ Wd2,
                     const float* __restrict__ Wm1, const float* __restrict__ Wm2,
                     const float* __restrict__ Wf1, const float* __restrict__ Wf2,
                     __bf16* __restrict__ wb) {
    __shared__ float t[8320];
    int m = blockIdx.x;
    const float* src; __bf16* dst; int R, C;
    if      (m < 37)  { src = Wi1 + m * 8192;        dst = wb + OFF_WI1T + m * 8192;        R = 64;  C = 128; }
    else if (m < 74)  { src = Wi2 + (m-37) * 8192;   dst = wb + OFF_WI2T + (m-37) * 8192;   R = 128; C = 64;  }
    else if (m < 111) { src = Wc1 + (m-74) * 8192;   dst = wb + OFF_WC1T + (m-74) * 8192;   R = 64;  C = 128; }
    else if (m < 148) { src = Wc2 + (m-111) * 8192;  dst = wb + OFF_WC2T + (m-111) * 8192;  R = 128; C = 64;  }
    else if (m < 185) { src = Wf1 + (m-148) * 8192;  dst = wb + OFF_WF1T + (m-148) * 8192;  R = 64;  C = 128; }
    else if (m < 222) { src = Wf2 + (m-185) * 8192;  dst = wb + OFF_WF2T + (m-185) * 8192;  R = 128; C = 64;  }
    else if (m < 238) { src = Wd1 + (m-222) * 8192;  dst = wb + OFF_WD1T + (m-222) * 8192;  R = 64;  C = 128; }
    else if (m < 254) { src = Wd2 + (m-238) * 8192;  dst = wb + OFF_WD2T + (m-238) * 8192;  R = 128; C = 64;  }
    else if (m < 270) { src = Wm1 + (m-254) * 8192;  dst = wb + OFF_WM1T + (m-254) * 8192;  R = 64;  C = 128; }
    else if (m < 286) { src = Wm2 + (m-270) * 8192;  dst = wb + OFF_WM2T + (m-270) * 8192;  R = 128; C = 64;  }
    else { const float* q3[3] = {Wq, Wk, Wv}; src = q3[m-286]; dst = wb + OFF_QKVT + (m-286) * 4096; R = 64; C = 64; }
    int n = R * C, Cp = C + 1;
    int logC = (C == 128) ? 7 : 6;
    int r16 = R >> 4, rmask = r16 - 1, rshift = (R == 128) ? 3 : 2;
    for (int i = threadIdx.x; i < n; i += 256)
        t[(i >> logC) * Cp + (i & (C - 1))] = src[i];
    __syncthreads();
    for (int o = threadIdx.x; o < n; o += 256) {
        int c = o / R, p = o & (R - 1);
        int kperm = (p & rmask) * 16 + (p >> rshift);
        dst[o] = (__bf16)t[kperm * Cp + c];
    }
}

// ---------------- main kernel ----------------

__device__ __forceinline__ bfrag zfrag() {
    bfrag r;
    #pragma unroll
    for (int j = 0; j < 8; ++j) r[j] = (__bf16)0.0f;
    return r;
}

// write X regs (C-layout, k-permuted cols) to bf16 image; b64 per (mt,r)
__device__ __forceinline__ void write_XI(const float Xr[2][4][4], __bf16* XI, int lq, int quad) {
    #pragma unroll
    for (int mt = 0; mt < 2; ++mt)
        #pragma unroll
        for (int r = 0; r < 4; ++r) {
            bf16x4 v;
            v[0] = (__bf16)Xr[mt][0][r]; v[1] = (__bf16)Xr[mt][1][r];
            v[2] = (__bf16)Xr[mt][2][r]; v[3] = (__bf16)Xr[mt][3][r];
            *(bf16x4*)&XI[(mt * 16 + quad * 4 + r) * 72 + lq * 4] = v;
        }
}

// x[32][64] += relu(x@W1+b1)@W2 + b2, X in regs, H staged k-permuted in RB
__device__ __forceinline__ void ffn2(float Xr[2][4][4], __bf16* XI, __bf16* H,
    const __bf16* __restrict__ W1t, const float* __restrict__ b1,
    const __bf16* __restrict__ W2t, const float* __restrict__ b2, int lq, int quad) {
    write_XI(Xr, XI, lq, quad);
    __syncthreads();
    bfrag a[2][2];
    #pragma unroll
    for (int mt = 0; mt < 2; ++mt)
        #pragma unroll
        for (int kf = 0; kf < 2; ++kf)
            a[mt][kf] = *(const bfrag*)&XI[(mt * 16 + lq) * 72 + kf * 32 + quad * 8];
    // layer 1: two groups of 4 N-tiles so H stores are b64
    #pragma unroll
    for (int g = 0; g < 2; ++g) {
        f32x4 acc[2][4];
        #pragma unroll
        for (int u = 0; u < 4; ++u) {
            float bv = b1[(g * 4 + u) * 16 + lq];
            acc[0][u] = (f32x4){bv, bv, bv, bv};
            acc[1][u] = acc[0][u];
        }
        #pragma unroll
        for (int u = 0; u < 4; ++u) {
            int nt = g * 4 + u;
            #pragma unroll
            for (int kf = 0; kf < 2; ++kf) {
                bfrag w = *(const bfrag*)(W1t + (nt * 16 + lq) * 64 + kf * 32 + quad * 8);
                acc[0][u] = MFMA16(a[0][kf], w, acc[0][u]);
                acc[1][u] = MFMA16(a[1][kf], w, acc[1][u]);
            }
        }
        #pragma unroll
        for (int mt = 0; mt < 2; ++mt)
            #pragma unroll
            for (int r = 0; r < 4; ++r) {
                bf16x4 hv;
                #pragma unroll
                for (int u = 0; u < 4; ++u) hv[u] = (__bf16)fmaxf(acc[mt][u][r], 0.0f);
                *(bf16x4*)&H[(mt * 16 + quad * 4 + r) * 136 + lq * 8 + g * 4] = hv;
            }
    }
    __syncthreads();
    bfrag a2[2][4];
    #pragma unroll
    for (int mt = 0; mt < 2; ++mt)
        #pragma unroll
        for (int kf = 0; kf < 4; ++kf)
            a2[mt][kf] = *(const bfrag*)&H[(mt * 16 + lq) * 136 + kf * 32 + quad * 8];
    #pragma unroll
    for (int nt = 0; nt < 4; ++nt) {
        float bv = b2[nt * 16 + lq];
        f32x4 acc0 = (f32x4){bv, bv, bv, bv}, acc1 = acc0;
        #pragma unroll
        for (int kf = 0; kf < 4; ++kf) {
            bfrag w = *(const bfrag*)(W2t + (nt * 16 + lq) * 128 + kf * 32 + quad * 8);
            acc0 = MFMA16(a2[0][kf], w, acc0);
            acc1 = MFMA16(a2[1][kf], w, acc1);
        }
        #pragma unroll
        for (int r = 0; r < 4; ++r) { Xr[0][nt][r] += acc0[r]; Xr[1][nt][r] += acc1[r]; }
    }
    __syncthreads();
}

// residual attention; stacked-slot block-diag P, PV adds straight into X regs
__device__ __forceinline__ void attn2(float Xr[2][4][4], __bf16* XI,
    __bf16* Qb, __bf16* Kb, __bf16* Vt, float* Sf, __bf16* P,
    const __bf16* __restrict__ qkvt, int lq, int quad) {
    int lane = quad * 16 + lq;
    write_XI(Xr, XI, lq, quad);
    __syncthreads();
    for (int c = 0; c < 2; ++c) {
        bfrag a[2];
        #pragma unroll
        for (int kf = 0; kf < 2; ++kf)
            a[kf] = *(const bfrag*)&XI[(c * 16 + lq) * 72 + kf * 32 + quad * 8];
        // Q, K, V projections (grouped to bound registers)
        #pragma unroll
        for (int grp = 0; grp < 3; ++grp) {
            f32x4 acc[4];
            #pragma unroll
            for (int nt = 0; nt < 4; ++nt) {
                acc[nt] = (f32x4){0.f, 0.f, 0.f, 0.f};
                #pragma unroll
                for (int kf = 0; kf < 2; ++kf) {
                    bfrag w = *(const bfrag*)(qkvt + (grp * 64 + nt * 16 + lq) * 64 + kf * 32 + quad * 8);
                    acc[nt] = MFMA16(a[kf], w, acc[nt]);
                }
            }
            if (grp < 2) {
                __bf16* dstb = (grp == 0) ? Qb : Kb;
                #pragma unroll
                for (int r = 0; r < 4; ++r) {
                    bf16x4 v;
                    #pragma unroll
                    for (int nt = 0; nt < 4; ++nt) v[nt] = (__bf16)acc[nt][r];
                    *(bf16x4*)&dstb[(quad * 4 + r) * 72 + lq * 4] = v;
                }
            } else {
                #pragma unroll
                for (int nt = 0; nt < 4; ++nt) {
                    bf16x4 v;
                    #pragma unroll
                    for (int r = 0; r < 4; ++r) v[r] = (__bf16)acc[nt][r];
                    *(bf16x4*)&Vt[(nt * 16 + lq) * 24 + quad * 4] = v;
                }
            }
        }
        __syncthreads();
        // S = Q K^T (16x16, includes cross-slot garbage; softmax reads own block)
        {
            bfrag qf0 = *(const bfrag*)&Qb[lq * 72 + quad * 8];
            bfrag qf1 = *(const bfrag*)&Qb[lq * 72 + 32 + quad * 8];
            bfrag kf0 = *(const bfrag*)&Kb[lq * 72 + quad * 8];
            bfrag kf1 = *(const bfrag*)&Kb[lq * 72 + 32 + quad * 8];
            f32x4 s = (f32x4){0.f, 0.f, 0.f, 0.f};
            s = MFMA16(qf0, kf0, s);
            s = MFMA16(qf1, kf1, s);
            #pragma unroll
            for (int r = 0; r < 4; ++r) Sf[(quad * 4 + r) * 20 + lq] = s[r] * 0.125f;
        }
        __syncthreads();
        if (lane < 16) {
            int m = lane, base = (m >> 3) * 8;
            f32x4 t0 = *(const f32x4*)&Sf[m * 20 + base];
            f32x4 t1 = *(const f32x4*)&Sf[m * 20 + base + 4];
            float e[8];
            #pragma unroll
            for (int j = 0; j < 4; ++j) { e[j] = t0[j]; e[4 + j] = t1[j]; }
            float mx = e[0];
            #pragma unroll
            for (int j = 1; j < 8; ++j) mx = fmaxf(mx, e[j]);
            float sum = 0.f;
            #pragma unroll
            for (int j = 0; j < 8; ++j) { e[j] = __expf(e[j] - mx); sum += e[j]; }
            float inv = 1.0f / sum;
            bfrag lo = zfrag(), hi = zfrag();
            #pragma unroll
            for (int j = 0; j < 8; ++j) {
                __bf16 pv = (__bf16)(e[j] * inv);
                if (m < 8) lo[j] = pv; else hi[j] = pv;
            }
            *(bfrag*)&P[m * 24] = lo;
            *(bfrag*)&P[m * 24 + 8] = hi;
        }
        __syncthreads();
        // out += P @ V  (k = stacked 16 positions; quads 2,3 zero-padded)
        bfrag pa = zfrag();
        if (quad < 2) pa = *(const bfrag*)&P[lq * 24 + quad * 8];
        #pragma unroll
        for (int nt = 0; nt < 4; ++nt) {
            bfrag vb = zfrag();
            if (quad < 2) vb = *(const bfrag*)&Vt[(nt * 16 + lq) * 24 + quad * 8];
            f32x4 o = (f32x4){0.f, 0.f, 0.f, 0.f};
            o = MFMA16(pa, vb, o);
            #pragma unroll
            for (int r = 0; r < 4; ++r) Xr[c][nt][r] += o[r];
        }
        __syncthreads();
    }
}

__global__ void __launch_bounds__(64, 3)
moe_main(const float* __restrict__ x, float* __restrict__ out,
         const int* __restrict__ cnt, const int* __restrict__ off,
         const int* __restrict__ rowIdx, const __bf16* __restrict__ wb,
         const float* __restrict__ bi1, const float* __restrict__ bi2,
         const float* __restrict__ bc1, const float* __restrict__ bc2,
         const float* __restrict__ bd1, const float* __restrict__ bd2,
         const float* __restrict__ bm1, const float* __restrict__ bm2,
         const float* __restrict__ bf1_, const float* __restrict__ bf2_) {
    __shared__ __align__(16) unsigned char RB[9728];
    __shared__ __align__(16) __bf16 XI[32 * 72];
    __bf16* H   = (__bf16*)RB;             // [32][136]
    float*  Xst = (float*)RB;              // [32][68] (init/final staging)
    __bf16* Qb  = (__bf16*)RB;             // [16][72]
    __bf16* Kb  = (__bf16*)(RB + 2304);    // [16][72]
    __bf16* Vt  = (__bf16*)(RB + 4608);    // [64][24]
    float*  Sf  = (float*)(RB + 7680);     // [16][20]
    __bf16* P   = (__bf16*)(RB + 8960);    // [16][24]

    int g = blockIdx.x;
    int lane = threadIdx.x, lq = lane & 15, quad = lane >> 4;

    int op = -1, tile = 0, acc_ = 0;
    for (int o = 0; o < NOPS; ++o) {
        int t = (cnt[o] + 3) >> 2;
        if (g < acc_ + t) { op = o; tile = g - acc_; break; }
        acc_ += t;
    }
    if (op < 0) return;
    int base = off[op] + tile * 4;
    int nr = cnt[op] - tile * 4; if (nr > 4) nr = 4;
    int rows[4];
    #pragma unroll
    for (int s = 0; s < 4; ++s) rows[s] = rowIdx[base + (s < nr ? s : nr - 1)];

    // stage x into Xst (coalesced float4), then build X regs (C-layout)
    for (int i = lane; i < 512; i += 64) {
        int s = i >> 7, rem = i & 127;
        float4 f4 = *(const float4*)&x[(size_t)rows[s] * 512 + rem * 4];
        *(float4*)&Xst[(s * 8 + (rem >> 4)) * 68 + (rem & 15) * 4] = f4;
    }
    __syncthreads();
    float Xr[2][4][4];
    #pragma unroll
    for (int mt = 0; mt < 2; ++mt)
        #pragma unroll
        for (int nt = 0; nt < 4; ++nt)
            #pragma unroll
            for (int r = 0; r < 4; ++r)
                Xr[mt][nt][r] = Xst[(mt * 16 + quad * 4 + r) * 68 + nt * 16 + lq];
    __syncthreads();

    // Stage 1
    ffn2(Xr, XI, H, wb + OFF_WI1T + op * 8192, bi1 + op * 128,
                    wb + OFF_WI2T + op * 8192, bi2 + op * 64, lq, quad);
    // Stages 2-3: carry cascade
    bool carry = (op <= 2) || (op >= 10 && op <= 13);
    if (carry) {
        const __bf16* qkvt = wb + OFF_QKVT;
        for (int it = 0; it < 7; ++it) {
            attn2(Xr, XI, Qb, Kb, Vt, Sf, P, qkvt, lq, quad);
            ffn2(Xr, XI, H, wb + OFF_WC1T + op * 8192, bc1 + op * 128,
                            wb + OFF_WC2T + op * 8192, bc2 + op * 64, lq, quad);
        }
    }
    if (op == 3) {
        for (int i = 0; i < 16; ++i)
            ffn2(Xr, XI, H, wb + OFF_WD1T + i * 8192, bd1 + i * 128,
                            wb + OFF_WD2T + i * 8192, bd2 + i * 64, lq, quad);
    }
    if (op == 4) {
        for (int i = 0; i < 16; ++i)
            ffn2(Xr, XI, H, wb + OFF_WM1T + i * 8192, bm1 + i * 128,
                            wb + OFF_WM2T + i * 8192, bm2 + i * 64, lq, quad);
    }
    // Stage 4
    ffn2(Xr, XI, H, wb + OFF_WF1T + op * 8192, bf1_ + op * 128,
                    wb + OFF_WF2T + op * 8192, bf2_ + op * 64, lq, quad);

    // X regs -> Xst -> coalesced global store
    #pragma unroll
    for (int mt = 0; mt < 2; ++mt)
        #pragma unroll
        for (int nt = 0; nt < 4; ++nt)
            #pragma unroll
            for (int r = 0; r < 4; ++r)
                Xst[(mt * 16 + quad * 4 + r) * 68 + nt * 16 + lq] = Xr[mt][nt][r];
    __syncthreads();
    for (int i = lane; i < nr * 128; i += 64) {
        int s = i >> 7, rem = i & 127;
        float4 f4 = *(const float4*)&Xst[(s * 8 + (rem >> 4)) * 68 + (rem & 15) * 4];
        *(float4*)&out[(size_t)rows[s] * 512 + rem * 4] = f4;
    }
}

// ---------------- launch ----------------

extern "C" void kernel_launch(void* const* d_in, const int* in_sizes, int n_in,
                              void* d_out, int out_size, void* d_ws, size_t ws_size,
                              hipStream_t stream) {
    (void)in_sizes; (void)n_in; (void)out_size; (void)ws_size;
    const float* x   = (const float*)d_in[0];
    const float* Wi1 = (const float*)d_in[1];
    const float* bi1 = (const float*)d_in[2];
    const float* Wi2 = (const float*)d_in[3];
    const float* bi2 = (const float*)d_in[4];
    const float* Wq  = (const float*)d_in[5];
    const float* Wk  = (const float*)d_in[6];
    const float* Wv  = (const float*)d_in[7];
    const float* Wc1 = (const float*)d_in[8];
    const float* bc1 = (const float*)d_in[9];
    const float* Wc2 = (const float*)d_in[10];
    const float* bc2 = (const float*)d_in[11];
    const float* Wd1 = (const float*)d_in[12];
    const float* bd1 = (const float*)d_in[13];
    const float* Wd2 = (const float*)d_in[14];
    const float* bd2 = (const float*)d_in[15];
    const float* Wm1 = (const float*)d_in[16];
    const float* bm1 = (const float*)d_in[17];
    const float* Wm2 = (const float*)d_in[18];
    const float* bm2 = (const float*)d_in[19];
    const float* Wf1 = (const float*)d_in[20];
    const float* bf1 = (const float*)d_in[21];
    const float* Wf2 = (const float*)d_in[22];
    const float* bf2 = (const float*)d_in[23];
    float* out = (float*)d_out;

    int* wsi    = (int*)d_ws;
    int* opArr  = wsi + WS_OPARR;
    int* cnt    = wsi + WS_CNT;
    int* off    = wsi + WS_OFF;
    int* cur    = wsi + WS_CUR;
    int* rowIdx = wsi + WS_ROWIDX;
    __bf16* wb  = (__bf16*)((char*)d_ws + WS_INTS * 4);

    k_zero<<<1, 64, 0, stream>>>(cnt, cur);
    k_op<<<NB / 4, 256, 0, stream>>>(x, opArr, cnt);
    k_scan<<<1, 64, 0, stream>>>(cnt, off);
    k_scatter<<<NB / 256, 256, 0, stream>>>(opArr, off, cur, rowIdx);
    k_wt<<<289, 256, 0, stream>>>(Wi1, Wi2, Wq, Wk, Wv, Wc1, Wc2, Wd1, Wd2, Wm1, Wm2, Wf1, Wf2, wb);
    moe_main<<<NB / 4 + NOPS, 64, 0, stream>>>(x, out, cnt, off, rowIdx, wb,
                                               bi1, bi2, bc1, bc2, bd1, bd2, bm1, bm2, bf1, bf2);
}

// Round 4
// 414.909 us; speedup vs baseline: 1.1899x; 1.1899x over previous
//
#include <hip/hip_runtime.h>
#include <math.h>

// SparseMoEALU R4: M=16 (2 rows/wave), 256-thr blocks, NO barriers in main
// kernel. Weights pre-transformed to frag-major bf16 (each lane's 16B MFMA
// B-fragment is lane-contiguous) -> perfectly coalesced global loads, no LDS
// staging. All per-wave LDS buffers; vector b64/b128 LDS ops only.

typedef __bf16 bfrag  __attribute__((ext_vector_type(8)));
typedef __bf16 bf16x4 __attribute__((ext_vector_type(4)));
typedef float  f32x4  __attribute__((ext_vector_type(4)));

#define MFMA16(a,b,c) __builtin_amdgcn_mfma_f32_16x16x32_bf16((a),(b),(c),0,0,0)

constexpr int NB = 16384, NOPS = 37, OP_START = 16;

// ws ints
constexpr int WS_OPARR  = 0;
constexpr int WS_CNT    = 16384;   // 64 ints
constexpr int WS_CUR    = 16448;   // 64 ints
constexpr int WS_ROWIDX = 16512;   // 16384 ints
constexpr int WS_INTS   = 32896;   // weight region at byte 131584 (16B aligned)

// bf16 elem offsets in frag-major weight region
constexpr int OFF_QKV = 0;         // 3 x 4096   (Q,K,V)
constexpr int OFF_I   = 12288;     // 37 x (W1 8192 | W2 8192)
constexpr int OFF_C   = 618496;    // 37 x 16384
constexpr int OFF_F   = 1224704;   // 37 x 16384
constexpr int OFF_D   = 1830912;   // 16 x 16384
constexpr int OFF_M   = 2093056;   // 16 x 16384

// ---------------- prep kernels ----------------

// frag-major transform: for W [R=K][C=N], emit frag f=(nt*KF+kf)*64+lane,
// elem j = W[kperm(kf*32+quad*8+j)][nt*16+lq]  (kperm matches XI/H pack order)
__global__ void k_wt(const float* __restrict__ Wi1, const float* __restrict__ Wi2,
                     const float* __restrict__ Wq,  const float* __restrict__ Wk,
                     const float* __restrict__ Wv,
                     const float* __restrict__ Wc1, const float* __restrict__ Wc2,
                     const float* __restrict__ Wd1, const float* __restrict__ Wd2,
                     const float* __restrict__ Wm1, const float* __restrict__ Wm2,
                     const float* __restrict__ Wf1, const float* __restrict__ Wf2,
                     __bf16* __restrict__ wb, int* __restrict__ cnt, int* __restrict__ cur) {
    __shared__ float t[8320];
    int m = blockIdx.x;
    if (m == 0 && threadIdx.x < NOPS) { cnt[threadIdx.x] = 0; cur[threadIdx.x] = 0; }
    const float* src; __bf16* dst; int R, C;
    if (m < 222) {
        int bank = m / 74;            // 0=I, 1=C, 2=F
        int r = m - bank * 74, op = r >> 1, which = r & 1;
        const float* s1[3] = {Wi1, Wc1, Wf1};
        const float* s2[3] = {Wi2, Wc2, Wf2};
        int obase[3] = {OFF_I, OFF_C, OFF_F};
        if (which == 0) { src = s1[bank] + op * 8192; R = 64;  C = 128; dst = wb + obase[bank] + op * 16384; }
        else            { src = s2[bank] + op * 8192; R = 128; C = 64;  dst = wb + obase[bank] + op * 16384 + 8192; }
    } else if (m < 286) {
        int bank = (m - 222) >> 5;    // 0=D, 1=M
        int r = (m - 222) & 31, it = r >> 1, which = r & 1;
        const float* s1 = bank ? Wm1 : Wd1;
        const float* s2 = bank ? Wm2 : Wd2;
        int obase = bank ? OFF_M : OFF_D;
        if (which == 0) { src = s1 + it * 8192; R = 64;  C = 128; dst = wb + obase + it * 16384; }
        else            { src = s2 + it * 8192; R = 128; C = 64;  dst = wb + obase + it * 16384 + 8192; }
    } else {
        const float* q3[3] = {Wq, Wk, Wv};
        src = q3[m - 286]; R = 64; C = 64; dst = wb + OFF_QKV + (m - 286) * 4096;
    }
    int n = R * C, Cp = C + 1, logC = (C == 128) ? 7 : 6;
    for (int i = threadIdx.x; i < n; i += 256)
        t[(i >> logC) * Cp + (i & (C - 1))] = src[i];
    __syncthreads();
    int KF = R >> 5;                  // 2 (K=64) or 4 (K=128)
    int nfrag = n >> 3;
    for (int f = threadIdx.x; f < nfrag; f += 256) {
        int lane_ = f & 63, fk = f >> 6;
        int kf = fk & (KF - 1), nt = fk >> (KF == 2 ? 1 : 2);
        int lq_ = lane_ & 15, quad_ = lane_ >> 4;
        int col = nt * 16 + lq_;
        bfrag v;
        #pragma unroll
        for (int j = 0; j < 8; ++j) {
            int ks = kf * 32 + quad_ * 8 + j;
            int k = (R == 64) ? ((ks & 3) * 16 + (ks >> 2)) : ((ks & 7) * 16 + (ks >> 3));
            v[j] = (__bf16)t[k * Cp + col];
        }
        *(bfrag*)&dst[f * 8] = v;
    }
}

__global__ void k_route(const float* __restrict__ x, int* __restrict__ opArr, int* __restrict__ cnt) {
    int wave = threadIdx.x >> 6, lane = threadIdx.x & 63;
    int row = blockIdx.x * 4 + wave;
    if (row >= NB) return;
    float av = (lane < NOPS) ? x[(size_t)row * 512 + OP_START + lane] : -INFINITY;
    int ai = lane;
    #pragma unroll
    for (int s = 1; s < 64; s <<= 1) {
        float ov = __shfl_xor(av, s);
        int   oi = __shfl_xor(ai, s);
        if (ov > av || (ov == av && oi < ai)) { av = ov; ai = oi; }
    }
    if (lane == 0) { opArr[row] = ai; atomicAdd(&cnt[ai], 1); }
}

__global__ void k_scatter(const int* __restrict__ opArr, const int* __restrict__ cnt,
                          int* __restrict__ cur, int* __restrict__ rowIdx) {
    int b = blockIdx.x * 256 + threadIdx.x;
    if (b >= NB) return;
    int op = opArr[b];
    int off = 0;
    for (int o = 0; o < op; ++o) off += cnt[o];
    int pos = off + atomicAdd(&cur[op], 1);
    rowIdx[pos] = b;
}

// ---------------- main kernel ----------------

__device__ __forceinline__ bfrag zfrag() {
    bfrag r;
    #pragma unroll
    for (int j = 0; j < 8; ++j) r[j] = (__bf16)0.0f;
    return r;
}

__device__ __forceinline__ void write_XI(const float Xr[4][4], __bf16* XI, int lq, int quad) {
    #pragma unroll
    for (int r = 0; r < 4; ++r) {
        bf16x4 v = { (__bf16)Xr[0][r], (__bf16)Xr[1][r], (__bf16)Xr[2][r], (__bf16)Xr[3][r] };
        *(bf16x4*)&XI[(quad * 4 + r) * 72 + lq * 4] = v;
    }
}

// X[16][64] += relu(X@W1+b1)@W2 + b2 ; weights frag-major in global
__device__ __forceinline__ void ffn_g(float Xr[4][4], __bf16* XI, __bf16* H,
    const __bf16* __restrict__ w1, const __bf16* __restrict__ w2,
    const float* __restrict__ b1, const float* __restrict__ b2,
    int lane, int lq, int quad) {
    write_XI(Xr, XI, lq, quad);
    bfrag a0 = *(const bfrag*)&XI[lq * 72 + quad * 8];
    bfrag a1 = *(const bfrag*)&XI[lq * 72 + 32 + quad * 8];
    #pragma unroll
    for (int g = 0; g < 2; ++g) {
        f32x4 acc[4];
        #pragma unroll
        for (int u = 0; u < 4; ++u) {
            float bv = b1[(g * 4 + u) * 16 + lq];
            acc[u] = (f32x4){bv, bv, bv, bv};
        }
        #pragma unroll
        for (int u = 0; u < 4; ++u) {
            int nt = g * 4 + u;
            bfrag w0 = *(const bfrag*)(w1 + ((nt * 2 + 0) * 64 + lane) * 8);
            bfrag wz = *(const bfrag*)(w1 + ((nt * 2 + 1) * 64 + lane) * 8);
            acc[u] = MFMA16(a0, w0, acc[u]);
            acc[u] = MFMA16(a1, wz, acc[u]);
        }
        #pragma unroll
        for (int r = 0; r < 4; ++r) {
            bf16x4 hv;
            #pragma unroll
            for (int u = 0; u < 4; ++u) hv[u] = (__bf16)fmaxf(acc[u][r], 0.0f);
            *(bf16x4*)&H[(quad * 4 + r) * 136 + lq * 8 + g * 4] = hv;
        }
    }
    bfrag h[4];
    #pragma unroll
    for (int kf = 0; kf < 4; ++kf)
        h[kf] = *(const bfrag*)&H[lq * 136 + kf * 32 + quad * 8];
    #pragma unroll
    for (int nt = 0; nt < 4; ++nt) {
        float bv = b2[nt * 16 + lq];
        f32x4 acc = (f32x4){bv, bv, bv, bv};
        #pragma unroll
        for (int kf = 0; kf < 4; ++kf) {
            bfrag w = *(const bfrag*)(w2 + ((nt * 4 + kf) * 64 + lane) * 8);
            acc = MFMA16(h[kf], w, acc);
        }
        #pragma unroll
        for (int r = 0; r < 4; ++r) Xr[nt][r] += acc[r];
    }
}

// residual attention over 8 positions of each of 2 rows (stacked-slot P/V)
__device__ __forceinline__ void attn_g(float Xr[4][4], __bf16* XI,
    __bf16* Qb, __bf16* Kb, __bf16* Vt, float* Sf, __bf16* Pp,
    const __bf16* __restrict__ qg, int lane, int lq, int quad) {
    write_XI(Xr, XI, lq, quad);
    bfrag a0 = *(const bfrag*)&XI[lq * 72 + quad * 8];
    bfrag a1 = *(const bfrag*)&XI[lq * 72 + 32 + quad * 8];
    // Q projection
    {
        f32x4 acc[4];
        #pragma unroll
        for (int nt = 0; nt < 4; ++nt) {
            acc[nt] = (f32x4){0.f, 0.f, 0.f, 0.f};
            bfrag w0 = *(const bfrag*)(qg + ((nt * 2 + 0) * 64 + lane) * 8);
            bfrag w1 = *(const bfrag*)(qg + ((nt * 2 + 1) * 64 + lane) * 8);
            acc[nt] = MFMA16(a0, w0, acc[nt]);
            acc[nt] = MFMA16(a1, w1, acc[nt]);
        }
        #pragma unroll
        for (int r = 0; r < 4; ++r) {
            bf16x4 v = { (__bf16)acc[0][r], (__bf16)acc[1][r], (__bf16)acc[2][r], (__bf16)acc[3][r] };
            *(bf16x4*)&Qb[(quad * 4 + r) * 72 + lq * 4] = v;
        }
    }
    // K projection
    {
        f32x4 acc[4];
        #pragma unroll
        for (int nt = 0; nt < 4; ++nt) {
            acc[nt] = (f32x4){0.f, 0.f, 0.f, 0.f};
            bfrag w0 = *(const bfrag*)(qg + (((4 + nt) * 2 + 0) * 64 + lane) * 8);
            bfrag w1 = *(const bfrag*)(qg + (((4 + nt) * 2 + 1) * 64 + lane) * 8);
            acc[nt] = MFMA16(a0, w0, acc[nt]);
            acc[nt] = MFMA16(a1, w1, acc[nt]);
        }
        #pragma unroll
        for (int r = 0; r < 4; ++r) {
            bf16x4 v = { (__bf16)acc[0][r], (__bf16)acc[1][r], (__bf16)acc[2][r], (__bf16)acc[3][r] };
            *(bf16x4*)&Kb[(quad * 4 + r) * 72 + lq * 4] = v;
        }
    }
    // S = Q K^T * 1/8 (16x16; cross-slot entries are garbage, never read)
    {
        bfrag q0 = *(const bfrag*)&Qb[lq * 72 + quad * 8];
        bfrag q1 = *(const bfrag*)&Qb[lq * 72 + 32 + quad * 8];
        bfrag k0 = *(const bfrag*)&Kb[lq * 72 + quad * 8];
        bfrag k1 = *(const bfrag*)&Kb[lq * 72 + 32 + quad * 8];
        f32x4 s = (f32x4){0.f, 0.f, 0.f, 0.f};
        s = MFMA16(q0, k0, s);
        s = MFMA16(q1, k1, s);
        #pragma unroll
        for (int r = 0; r < 4; ++r) Sf[(quad * 4 + r) * 20 + lq] = s[r] * 0.125f;
    }
    // softmax rows (lanes 0..15), write block-diag P
    if (lane < 16) {
        int m = lane, base = (m >> 3) * 8;
        f32x4 t0 = *(const f32x4*)&Sf[m * 20 + base];
        f32x4 t1 = *(const f32x4*)&Sf[m * 20 + base + 4];
        float e[8];
        #pragma unroll
        for (int j = 0; j < 4; ++j) { e[j] = t0[j]; e[4 + j] = t1[j]; }
        float mx = e[0];
        #pragma unroll
        for (int j = 1; j < 8; ++j) mx = fmaxf(mx, e[j]);
        float sum = 0.f;
        #pragma unroll
        for (int j = 0; j < 8; ++j) { e[j] = __expf(e[j] - mx); sum += e[j]; }
        float inv = 1.0f / sum;
        bfrag lo = zfrag(), hi = zfrag();
        #pragma unroll
        for (int j = 0; j < 8; ++j) {
            __bf16 pv = (__bf16)(e[j] * inv);
            if (m < 8) lo[j] = pv; else hi[j] = pv;
        }
        *(bfrag*)&Pp[m * 24] = lo;
        *(bfrag*)&Pp[m * 24 + 8] = hi;
    }
    // V projection (a0/a1 still live); Vt overlaps Qb/Kb (both consumed)
    {
        f32x4 acc[4];
        #pragma unroll
        for (int nt = 0; nt < 4; ++nt) {
            acc[nt] = (f32x4){0.f, 0.f, 0.f, 0.f};
            bfrag w0 = *(const bfrag*)(qg + (((8 + nt) * 2 + 0) * 64 + lane) * 8);
            bfrag w1 = *(const bfrag*)(qg + (((8 + nt) * 2 + 1) * 64 + lane) * 8);
            acc[nt] = MFMA16(a0, w0, acc[nt]);
            acc[nt] = MFMA16(a1, w1, acc[nt]);
        }
        #pragma unroll
        for (int nt = 0; nt < 4; ++nt) {
            bf16x4 v = { (__bf16)acc[nt][0], (__bf16)acc[nt][1], (__bf16)acc[nt][2], (__bf16)acc[nt][3] };
            *(bf16x4*)&Vt[(nt * 16 + lq) * 24 + quad * 4] = v;
        }
    }
    // out += P @ V (K=32 instr, upper 16 k zero via zfrag on quads 2,3)
    bfrag pa = zfrag();
    if (quad < 2) pa = *(const bfrag*)&Pp[lq * 24 + quad * 8];
    #pragma unroll
    for (int nt = 0; nt < 4; ++nt) {
        bfrag vb = zfrag();
        if (quad < 2) vb = *(const bfrag*)&Vt[(nt * 16 + lq) * 24 + quad * 8];
        f32x4 o = (f32x4){0.f, 0.f, 0.f, 0.f};
        o = MFMA16(pa, vb, o);
        #pragma unroll
        for (int r = 0; r < 4; ++r) Xr[nt][r] += o[r];
    }
}

__global__ void __launch_bounds__(256, 3)
moe_main(const float* __restrict__ x, float* __restrict__ out,
         const int* __restrict__ cnt, const int* __restrict__ rowIdx,
         const __bf16* __restrict__ wb,
         const float* __restrict__ bi1, const float* __restrict__ bi2,
         const float* __restrict__ bc1, const float* __restrict__ bc2,
         const float* __restrict__ bd1, const float* __restrict__ bd2,
         const float* __restrict__ bm1, const float* __restrict__ bm2,
         const float* __restrict__ bf1_, const float* __restrict__ bf2_) {
    __shared__ __align__(16) unsigned char SM[4 * 6912];   // 27648 B, all per-wave
    int lane = threadIdx.x & 63, wid = threadIdx.x >> 6;
    int lq = lane & 15, quad = lane >> 4;
    unsigned char* PW = SM + wid * 6912;
    __bf16* XI = (__bf16*)PW;                 // [16][72] 2304 B
    float*  Sf = (float*)PW;                  // [16][20] 1280 B (overlaps XI, time-disjoint)
    __bf16* Pp = (__bf16*)(PW + 1280);        // [16][24] 768 B
    unsigned char* U = PW + 2304;             // 4608 B union
    __bf16* H  = (__bf16*)U;                  // [16][136] 4352 B (FFN)
    float*  Uf = (float*)U;                   // [16][68] 4352 B (I/O staging)
    __bf16* Qb = (__bf16*)U;                  // [16][72] 2304 B (attn)
    __bf16* Kb = (__bf16*)(U + 2304);         // [16][72]
    __bf16* Vt = (__bf16*)U;                  // [64][24] 3072 B (after Q/K consumed)

    // block -> (op, local block) mapping; 8 rows per block (2 per wave)
    int g = blockIdx.x;
    int op = -1, lb = 0, csum = 0, obase = 0;
    for (int o = 0; o < NOPS; ++o) {
        int c = cnt[o];
        int nb = (c + 7) >> 3;
        if (g < csum + nb) { op = o; lb = g - csum; break; }
        csum += nb; obase += c;
    }
    if (op < 0) return;
    int c = cnt[op];
    int i0 = lb * 8 + wid * 2, i1 = i0 + 1;
    if (i0 >= c) i0 = c - 1;
    if (i1 >= c) i1 = c - 1;
    int r0 = rowIdx[obase + i0], r1 = rowIdx[obase + i1];

    // load 2 rows (coalesced float4) into Uf, then X regs (C-layout)
    int rows2[2] = {r0, r1};
    #pragma unroll
    for (int i = 0; i < 4; ++i) {
        int idx = i * 64 + lane, s = idx >> 7, rem = idx & 127;
        float4 f4 = *(const float4*)&x[(size_t)rows2[s] * 512 + rem * 4];
        *(float4*)&Uf[(s * 8 + (rem >> 4)) * 68 + (rem & 15) * 4] = f4;
    }
    float Xr[4][4];
    #pragma unroll
    for (int nt = 0; nt < 4; ++nt)
        #pragma unroll
        for (int r = 0; r < 4; ++r)
            Xr[nt][r] = Uf[(quad * 4 + r) * 68 + nt * 16 + lq];

    // Stage 1: initial experts
    ffn_g(Xr, XI, H, wb + OFF_I + op * 16384, wb + OFF_I + op * 16384 + 8192,
          bi1 + op * 128, bi2 + op * 64, lane, lq, quad);
    // Stages 2-3: carry cascade (7x attn+ffn)
    bool carry = (op <= 2) || (op >= 10 && op <= 13);
    if (carry) {
        const __bf16* qg = wb + OFF_QKV;
        const __bf16* w1 = wb + OFF_C + op * 16384;
        const __bf16* w2 = w1 + 8192;
        for (int it = 0; it < 7; ++it) {
            attn_g(Xr, XI, Qb, Kb, Vt, Sf, Pp, qg, lane, lq, quad);
            ffn_g(Xr, XI, H, w1, w2, bc1 + op * 128, bc2 + op * 64, lane, lq, quad);
        }
    }
    // 16 DIV / MOD iterative FFNs
    if (op == 3) {
        for (int i = 0; i < 16; ++i)
            ffn_g(Xr, XI, H, wb + OFF_D + i * 16384, wb + OFF_D + i * 16384 + 8192,
                  bd1 + i * 128, bd2 + i * 64, lane, lq, quad);
    }
    if (op == 4) {
        for (int i = 0; i < 16; ++i)
            ffn_g(Xr, XI, H, wb + OFF_M + i * 16384, wb + OFF_M + i * 16384 + 8192,
                  bm1 + i * 128, bm2 + i * 64, lane, lq, quad);
    }
    // Stage 4: final experts
    ffn_g(Xr, XI, H, wb + OFF_F + op * 16384, wb + OFF_F + op * 16384 + 8192,
          bf1_ + op * 128, bf2_ + op * 64, lane, lq, quad);

    // X regs -> Uf -> coalesced store
    #pragma unroll
    for (int nt = 0; nt < 4; ++nt)
        #pragma unroll
        for (int r = 0; r < 4; ++r)
            Uf[(quad * 4 + r) * 68 + nt * 16 + lq] = Xr[nt][r];
    #pragma unroll
    for (int i = 0; i < 4; ++i) {
        int idx = i * 64 + lane, s = idx >> 7, rem = idx & 127;
        float4 f4 = *(const float4*)&Uf[(s * 8 + (rem >> 4)) * 68 + (rem & 15) * 4];
        *(float4*)&out[(size_t)rows2[s] * 512 + rem * 4] = f4;
    }
}

// ---------------- launch ----------------

extern "C" void kernel_launch(void* const* d_in, const int* in_sizes, int n_in,
                              void* d_out, int out_size, void* d_ws, size_t ws_size,
                              hipStream_t stream) {
    (void)in_sizes; (void)n_in; (void)out_size; (void)ws_size;
    const float* x   = (const float*)d_in[0];
    const float* Wi1 = (const float*)d_in[1];
    const float* bi1 = (const float*)d_in[2];
    const float* Wi2 = (const float*)d_in[3];
    const float* bi2 = (const float*)d_in[4];
    const float* Wq  = (const float*)d_in[5];
    const float* Wk  = (const float*)d_in[6];
    const float* Wv  = (const float*)d_in[7];
    const float* Wc1 = (const float*)d_in[8];
    const float* bc1 = (const float*)d_in[9];
    const float* Wc2 = (const float*)d_in[10];
    const float* bc2 = (const float*)d_in[11];
    const float* Wd1 = (const float*)d_in[12];
    const float* bd1 = (const float*)d_in[13];
    const float* Wd2 = (const float*)d_in[14];
    const float* bd2 = (const float*)d_in[15];
    const float* Wm1 = (const float*)d_in[16];
    const float* bm1 = (const float*)d_in[17];
    const float* Wm2 = (const float*)d_in[18];
    const float* bm2 = (const float*)d_in[19];
    const float* Wf1 = (const float*)d_in[20];
    const float* bf1 = (const float*)d_in[21];
    const float* Wf2 = (const float*)d_in[22];
    const float* bf2 = (const float*)d_in[23];
    float* out = (float*)d_out;

    int* wsi    = (int*)d_ws;
    int* opArr  = wsi + WS_OPARR;
    int* cnt    = wsi + WS_CNT;
    int* cur    = wsi + WS_CUR;
    int* rowIdx = wsi + WS_ROWIDX;
    __bf16* wb  = (__bf16*)((char*)d_ws + WS_INTS * 4);

    k_wt<<<289, 256, 0, stream>>>(Wi1, Wi2, Wq, Wk, Wv, Wc1, Wc2, Wd1, Wd2,
                                  Wm1, Wm2, Wf1, Wf2, wb, cnt, cur);
    k_route<<<NB / 4, 256, 0, stream>>>(x, opArr, cnt);
    k_scatter<<<NB / 256, 256, 0, stream>>>(opArr, cnt, cur, rowIdx);
    moe_main<<<NB / 8 + NOPS, 256, 0, stream>>>(x, out, cnt, rowIdx, wb,
                                                bi1, bi2, bc1, bc2, bd1, bd2,
                                                bm1, bm2, bf1, bf2);
}